// Round 15
// baseline (6045.975 us; speedup 1.0000x reference)
//
#include <hip/hip_runtime.h>

#define S_LEN 16384
#define BATCH 128
#define HID   128
#define NTHR  256
#define CHUNK 256
#define NCHUNK (S_LEN / CHUNK)

#define K2LOG2E 2.8853900817779268f   // 2*log2(e)

typedef float f2 __attribute__((ext_vector_type(2)));

// Compiler-generated lane broadcast (hazard handling by LLVM).
__device__ __forceinline__ float rdlane(float v, int lane) {
    return __uint_as_float(__builtin_amdgcn_readlane(__float_as_uint(v), lane));
}

// One block = one chain: 256 threads = 4 waves, 1 wave/SIMD.
// K split ACROSS waves (wave w owns rows [32w,32w+32)); lane l owns units
// jA=l, jB=l+64; weights row-packed {W2[i][jA],W2[i][jB]} as 32 f2 =
// 64 arch VGPRs (resident: VGPR_Count=132, R10-R14). h1 broadcast via
// readlane (VALU pipe); single barrier per step for the pv exchange
// (layout [w][l] f2 -> 2-way bank aliasing = free; any b128-friendly
// transpose is provably >=8-way conflicted, analyzed R15).
// ROUND-15: revert to R13's measured-better placement (off-path work in
// the PRE-barrier drain window) + fold 2log2e & biases into every serial
// hinge: tanh1 gets zK = fmaf(c1K, sv, preK) straight into exp2 (the
// sv->h1 hinge loses its serial multiply); tanh2 gets fmaf(q,K,b2K);
// the W3 dot consumes rcp outputs directly via p = m3A*rA + m3B*rB + w3s.
__attribute__((amdgpu_waves_per_eu(1, 1)))
__global__ __launch_bounds__(NTHR, 1) void ode_scan_kernel(
    const float* __restrict__ x,
    const float* __restrict__ W1, const float* __restrict__ b1,
    const float* __restrict__ W2, const float* __restrict__ b2,
    const float* __restrict__ W3, const float* __restrict__ b3,
    float* __restrict__ out)
{
    const int tid  = threadIdx.x;
    const int bb   = blockIdx.x;     // batch chain index
    const int l    = tid & 63;       // lane
    const int w    = tid >> 6;       // wave = K-quarter
    const int koff = w << 5;         // first K-row of this wave
    const int jA   = l;              // owned units
    const int jB   = l + 64;
    const int row  = koff + (l & 31);// layer-1 row (lanes 32.. duplicate)

    __shared__ __align__(16) f2    lds_p[2][4][64]; // [par][wave][lane]={pA,pB}
    __shared__ float lds_x[2][CHUNK];

    // layer-1 constants for this lane's K-row (K-prescaled for tanh1)
    const float c1  = W1[row];          // y coefficient (row 0 of W1)
    const float w1x = W1[HID + row];    // x coefficient (row 1 of W1)
    const float b1r = b1[row];
    const float c1K = c1 * K2LOG2E;
    // layer-2/3 constants for the two owned units (K-prescaled for tanh2,
    // W3 folded to consume rcp outputs directly: h2 = 1-2r -> p = sum of
    // w3*(1-2r) = (w3A+w3B) - 2w3A*rA - 2w3B*rB)
    const float b2AK = b2[jA] * K2LOG2E, b2BK = b2[jB] * K2LOG2E;
    const float w3A = W3[jA], w3B = W3[jB];
    const float m3A = -2.0f * w3A, m3B = -2.0f * w3B;
    const float w3s = w3A + w3B;
    const float b3s = b3[0];

    // 32 rows x {unitA, unitB}: w##r##_##t = {W2[koff+4r+t][jA], ..[jB]}.
#define REP8(M) M(0) M(1) M(2) M(3) M(4) M(5) M(6) M(7)
#define DECLW(r) \
    f2 w##r##_0 = { W2[(koff+4*(r)+0)*HID + jA], W2[(koff+4*(r)+0)*HID + jB] }; \
    f2 w##r##_1 = { W2[(koff+4*(r)+1)*HID + jA], W2[(koff+4*(r)+1)*HID + jB] }; \
    f2 w##r##_2 = { W2[(koff+4*(r)+2)*HID + jA], W2[(koff+4*(r)+2)*HID + jB] }; \
    f2 w##r##_3 = { W2[(koff+4*(r)+3)*HID + jA], W2[(koff+4*(r)+3)*HID + jB] };
    REP8(DECLW)

    // Preload x chunk 0: lds_x[0][t] = x[t][bb].
    lds_x[0][tid] = x[tid * BATCH + bb];
    __syncthreads();

    // Carried state: y = y_n, sv = last step's raw DPP sum (pre-b3),
    // preK = K*(c1*(y_n+b3s) + ax_n), so tanh1's exp2 arg = fmaf(c1K,sv,preK).
    float y    = 0.0f;
    float ycap = 0.0f;
    float sv   = 0.0f;
    float preK = fmaf(w1x, lds_x[0][0], b1r) * K2LOG2E;  // K*ax_0
    int   cur  = 0;

    for (int c = 0; c < NCHUNK; ++c) {
        // Refill other x buffer with next chunk (dup-load last, unused).
        int nb = (c + 1 < NCHUNK) ? (c + 1) : c;
        float xf = x[(nb * CHUNK + tid) * BATCH + bb];
        lds_x[cur ^ 1][tid] = xf;

#pragma unroll 2
        for (int s = 0; s < CHUNK; ++s) {
            // ---- layer 1: e = exp2(K*z), h1 = 1 - 2/(e+1) ----
            float e1 = __builtin_amdgcn_exp2f(fmaf(c1K, sv, preK));
            float h1 = fmaf(-2.0f, __builtin_amdgcn_rcpf(e1 + 1.0f), 1.0f);

            y += fmaf(0.0f, 0.0f, sv);     // y_n update, off critical path
            // (kept as plain add; see epilogue for final y+b3 handling)

            // ---- layer 2 (quarter-K x 2 units): readlane broadcast +
            //      one pk-FMA per row covering both units ----
            f2 a0 = {0.f,0.f}, a1 = {0.f,0.f}, a2 = {0.f,0.f}, a3 = {0.f,0.f};
#define MACR(r) { \
            float h0_ = rdlane(h1, 4*(r)+0); f2 s0_ = { h0_, h0_ }; \
            a0 = __builtin_elementwise_fma(s0_, w##r##_0, a0); \
            float h1_ = rdlane(h1, 4*(r)+1); f2 s1_ = { h1_, h1_ }; \
            a1 = __builtin_elementwise_fma(s1_, w##r##_1, a1); \
            float h2_ = rdlane(h1, 4*(r)+2); f2 s2_ = { h2_, h2_ }; \
            a2 = __builtin_elementwise_fma(s2_, w##r##_2, a2); \
            float h3_ = rdlane(h1, 4*(r)+3); f2 s3_ = { h3_, h3_ }; \
            a3 = __builtin_elementwise_fma(s3_, w##r##_3, a3); }
            REP8(MACR)

            f2 pv = (a0 + a1) + (a2 + a3);   // {pA, pB} for this K-quarter

            // ---- publish partials ASAP ----
            const int buf = s & 1;           // static under unroll 2
            lds_p[buf][w][l] = pv;           // ds_write_b64

            // ---- off-path work fills the pre-barrier drain window ----
            float xn  = (s < CHUNK - 1) ? lds_x[cur][s + 1] : lds_x[cur ^ 1][0];
            float yb  = y + b3s;             // y_n + b3 (off-path)
            float axn = fmaf(w1x, xn, b1r);  // ax_{n+1} (off-path)
            preK = fmaf(c1, yb, axn) * K2LOG2E;  // K*(c1*(y_n+b3s)+ax_{n+1})

            __syncthreads();                 // the ONE barrier per step

            // ---- finish: all 4 waves redundantly, bit-identical ----
            f2 r0 = lds_p[buf][0][l];
            f2 r1 = lds_p[buf][1][l];
            f2 r2 = lds_p[buf][2][l];
            f2 r3 = lds_p[buf][3][l];
            f2 q  = (r0 + r1) + (r2 + r3);   // {sum_jA, sum_jB} over K=128
            float eA = __builtin_amdgcn_exp2f(fmaf(q.x, K2LOG2E, b2AK));
            float eB = __builtin_amdgcn_exp2f(fmaf(q.y, K2LOG2E, b2BK));
            float rA = __builtin_amdgcn_rcpf(eA + 1.0f);
            float rB = __builtin_amdgcn_rcpf(eB + 1.0f);
            // p = w3A*tanhA + w3B*tanhB = w3s + m3A*rA + m3B*rB
            float p  = fmaf(m3A, rA, fmaf(m3B, rB, w3s));

            // 64-lane DPP sum (covers all 128 units) -> lane 63
            asm volatile(
                "s_nop 1\n\t"
                "v_add_f32 %0, %0, %0 row_shr:1 bound_ctrl:0\n\t"
                "s_nop 1\n\t"
                "v_add_f32 %0, %0, %0 row_shr:2 bound_ctrl:0\n\t"
                "s_nop 1\n\t"
                "v_add_f32 %0, %0, %0 row_shr:4 bank_mask:0xe\n\t"
                "s_nop 1\n\t"
                "v_add_f32 %0, %0, %0 row_shr:8 bank_mask:0xc\n\t"
                "s_nop 1\n\t"
                "v_add_f32 %0, %0, %0 row_bcast:15 row_mask:0xa\n\t"
                "s_nop 1\n\t"
                "v_add_f32 %0, %0, %0 row_bcast:31 row_mask:0xc\n\t"
                : "+v"(p));
            sv = rdlane(p, 63);              // raw Δ (pre-b3); feeds next h1

            ycap = (tid == s) ? (y + b3s + sv) : ycap;  // y_{n+1} capture
        }
        out[(c * CHUNK + tid) * BATCH + bb] = ycap;   // 256 steps per store
        cur ^= 1;
    }
}

extern "C" void kernel_launch(void* const* d_in, const int* in_sizes, int n_in,
                              void* d_out, int out_size, void* d_ws, size_t ws_size,
                              hipStream_t stream) {
    const float* x  = (const float*)d_in[0];
    const float* W1 = (const float*)d_in[1];
    const float* b1 = (const float*)d_in[2];
    const float* W2 = (const float*)d_in[3];
    const float* b2 = (const float*)d_in[4];
    const float* W3 = (const float*)d_in[5];
    const float* b3 = (const float*)d_in[6];
    float* out = (float*)d_out;

    hipLaunchKernelGGL(ode_scan_kernel, dim3(BATCH), dim3(NTHR), 0, stream,
                       x, W1, b1, W2, b2, W3, b3, out);
}

// Round 16
// 5930.657 us; speedup vs baseline: 1.0194x; 1.0194x over previous
//
#include <hip/hip_runtime.h>

#define S_LEN 16384
#define BATCH 128
#define HID   128
#define NTHR  256
#define CHUNK 256
#define NCHUNK (S_LEN / CHUNK)

typedef float f2 __attribute__((ext_vector_type(2)));

// Clamp-free tanh: tanh(z) = 1 - 2/(e^{2z}+1).
__device__ __forceinline__ float fast_tanh(float z) {
    float e = __builtin_amdgcn_exp2f(z * 2.8853900817779268f);
    return fmaf(-2.0f, __builtin_amdgcn_rcpf(e + 1.0f), 1.0f);
}

// Compiler-generated lane broadcast (hazard handling by LLVM).
__device__ __forceinline__ float rdlane(float v, int lane) {
    return __uint_as_float(__builtin_amdgcn_readlane(__float_as_uint(v), lane));
}

// One block = one chain: 256 threads = 4 waves, 1 wave/SIMD.
// K split ACROSS waves (wave w owns rows [32w,32w+32)); lane l owns units
// jA=l, jB=l+64; weights row-packed {W2[i][jA],W2[i][jB]} as 32 f2 =
// 64 arch VGPRs (resident: VGPR_Count=132 since R10). h1 broadcast via
// readlane (VALU pipe, R13); ONE barrier per step for the pv exchange.
// ROUND-16 = exact R13 + ONE change: the xn LDS read is ISSUED at the top
// of the step (before the ~200-cyc MAC phase) and CONSUMED pre-barrier.
// In R13 it was issued ~10 cyc before __syncthreads, so the compiler's
// mandatory `s_waitcnt lgkmcnt(0)` barrier-drain ate its full ~100-cyc DS
// latency every step. Issued early, it completes under the MAC and the
// drain covers only the pv ds_write.
__attribute__((amdgpu_waves_per_eu(1, 1)))
__global__ __launch_bounds__(NTHR, 1) void ode_scan_kernel(
    const float* __restrict__ x,
    const float* __restrict__ W1, const float* __restrict__ b1,
    const float* __restrict__ W2, const float* __restrict__ b2,
    const float* __restrict__ W3, const float* __restrict__ b3,
    float* __restrict__ out)
{
    const int tid  = threadIdx.x;
    const int bb   = blockIdx.x;     // batch chain index
    const int l    = tid & 63;       // lane
    const int w    = tid >> 6;       // wave = K-quarter
    const int koff = w << 5;         // first K-row of this wave
    const int jA   = l;              // owned units
    const int jB   = l + 64;
    const int row  = koff + (l & 31);// layer-1 row (lanes 32.. duplicate)

    __shared__ __align__(16) f2    lds_p[2][4][64]; // [par][wave][lane]={pA,pB}
    __shared__ float lds_x[2][CHUNK];

    // layer-1 constants for this lane's K-row
    const float c1  = W1[row];          // y coefficient (row 0 of W1)
    const float w1x = W1[HID + row];    // x coefficient (row 1 of W1)
    const float b1r = b1[row];
    // layer-2/3 constants for the two owned units
    const float b2A = b2[jA], b2B = b2[jB];
    const float w3A = W3[jA], w3B = W3[jB];
    const float b3s = b3[0];

    // 32 rows x {unitA, unitB}: w##r##_##t = {W2[koff+4r+t][jA], ..[jB]}.
#define REP8(M) M(0) M(1) M(2) M(3) M(4) M(5) M(6) M(7)
#define DECLW(r) \
    f2 w##r##_0 = { W2[(koff+4*(r)+0)*HID + jA], W2[(koff+4*(r)+0)*HID + jB] }; \
    f2 w##r##_1 = { W2[(koff+4*(r)+1)*HID + jA], W2[(koff+4*(r)+1)*HID + jB] }; \
    f2 w##r##_2 = { W2[(koff+4*(r)+2)*HID + jA], W2[(koff+4*(r)+2)*HID + jB] }; \
    f2 w##r##_3 = { W2[(koff+4*(r)+3)*HID + jA], W2[(koff+4*(r)+3)*HID + jB] };
    REP8(DECLW)

    // Preload x chunk 0: lds_x[0][t] = x[t][bb].
    lds_x[0][tid] = x[tid * BATCH + bb];
    __syncthreads();

    // Carried state: y (pre-update), svb (last step's Δy), base (= c1*y + ax
    // for the CURRENT step), ycap (captured output history).
    float y    = 0.0f;
    float ycap = 0.0f;
    float svb  = 0.0f;
    float base = fmaf(w1x, lds_x[0][0], b1r);  // = ax_0 (y_0 = 0)
    int   cur  = 0;

    for (int c = 0; c < NCHUNK; ++c) {
        // Refill other x buffer with next chunk (dup-load last, unused).
        int nb = (c + 1 < NCHUNK) ? (c + 1) : c;
        float xf = x[(nb * CHUNK + tid) * BATCH + bb];
        lds_x[cur ^ 1][tid] = xf;

#pragma unroll 1
        for (int s = 0; s < CHUNK; ++s) {
            // ---- layer 1: z = c1*y_n + ax_n = base + c1*svb_{n-1} ----
            float h1 = fast_tanh(fmaf(c1, svb, base));

            // ---- ISSUE next-x read NOW (consumed pre-barrier, ~200 cyc
            //      later): its DS latency hides under the MAC phase and
            //      stays clear of the barrier's lgkmcnt(0) drain ----
            float xn = (s < CHUNK - 1) ? lds_x[cur][s + 1] : lds_x[cur ^ 1][0];

            y += svb;                  // y_n (off critical path)

            // ---- layer 2 (quarter-K x 2 units): readlane broadcast +
            //      one pk-FMA per row covering both units ----
            f2 a0 = {0.f,0.f}, a1 = {0.f,0.f}, a2 = {0.f,0.f}, a3 = {0.f,0.f};
#define MACR(r) { \
            float h0_ = rdlane(h1, 4*(r)+0); f2 s0_ = { h0_, h0_ }; \
            a0 = __builtin_elementwise_fma(s0_, w##r##_0, a0); \
            float h1_ = rdlane(h1, 4*(r)+1); f2 s1_ = { h1_, h1_ }; \
            a1 = __builtin_elementwise_fma(s1_, w##r##_1, a1); \
            float h2_ = rdlane(h1, 4*(r)+2); f2 s2_ = { h2_, h2_ }; \
            a2 = __builtin_elementwise_fma(s2_, w##r##_2, a2); \
            float h3_ = rdlane(h1, 4*(r)+3); f2 s3_ = { h3_, h3_ }; \
            a3 = __builtin_elementwise_fma(s3_, w##r##_3, a3); }
            REP8(MACR)

            f2 pv = (a0 + a1) + (a2 + a3);   // {pA, pB} for this K-quarter

            // ---- publish partials ASAP ----
            const int buf = s & 1;           // parity double-buffer: WAR-safe
            lds_p[buf][w][l] = pv;           // ds_write_b64

            // ---- off-path consumers fill the pre-barrier window ----
            float axn = fmaf(w1x, xn, b1r);  // ax_{n+1} (xn long since landed)
            base = fmaf(c1, y, axn);         // c1*y_n + ax_{n+1}

            __syncthreads();                 // the ONE barrier per step

            // ---- finish: all 4 waves redundantly, bit-identical ----
            f2 r0 = lds_p[buf][0][l];
            f2 r1 = lds_p[buf][1][l];
            f2 r2 = lds_p[buf][2][l];
            f2 r3 = lds_p[buf][3][l];
            f2 q  = (r0 + r1) + (r2 + r3);   // {sum_jA, sum_jB} over K=128
            float h2A = fast_tanh(q.x + b2A);
            float h2B = fast_tanh(q.y + b2B);
            float p   = fmaf(h2A, w3A, h2B * w3B);

            // 64-lane DPP sum (covers all 128 units) -> lane 63
            asm volatile(
                "s_nop 1\n\t"
                "v_add_f32 %0, %0, %0 row_shr:1 bound_ctrl:0\n\t"
                "s_nop 1\n\t"
                "v_add_f32 %0, %0, %0 row_shr:2 bound_ctrl:0\n\t"
                "s_nop 1\n\t"
                "v_add_f32 %0, %0, %0 row_shr:4 bank_mask:0xe\n\t"
                "s_nop 1\n\t"
                "v_add_f32 %0, %0, %0 row_shr:8 bank_mask:0xc\n\t"
                "s_nop 1\n\t"
                "v_add_f32 %0, %0, %0 row_bcast:15 row_mask:0xa\n\t"
                "s_nop 1\n\t"
                "v_add_f32 %0, %0, %0 row_bcast:31 row_mask:0xc\n\t"
                : "+v"(p));
            float sv = rdlane(p, 63);        // compiler readlane (hazard-safe)

            svb = sv + b3s;                  // Δy_n; feeds next layer-1 directly
            ycap = (tid == s) ? (y + svb) : ycap;  // y_{n+1} capture (off-path)
        }
        out[(c * CHUNK + tid) * BATCH + bb] = ycap;   // 256 steps per store
        cur ^= 1;
    }
}

extern "C" void kernel_launch(void* const* d_in, const int* in_sizes, int n_in,
                              void* d_out, int out_size, void* d_ws, size_t ws_size,
                              hipStream_t stream) {
    const float* x  = (const float*)d_in[0];
    const float* W1 = (const float*)d_in[1];
    const float* b1 = (const float*)d_in[2];
    const float* W2 = (const float*)d_in[3];
    const float* b2 = (const float*)d_in[4];
    const float* W3 = (const float*)d_in[5];
    const float* b3 = (const float*)d_in[6];
    float* out = (float*)d_out;

    hipLaunchKernelGGL(ode_scan_kernel, dim3(BATCH), dim3(NTHR), 0, stream,
                       x, W1, b1, W2, b2, W3, b3, out);
}

// Round 17
// 5805.630 us; speedup vs baseline: 1.0414x; 1.0215x over previous
//
#include <hip/hip_runtime.h>

#define S_LEN 16384
#define BATCH 128
#define HID   128
#define NTHR  256
#define CHUNK 256
#define NCHUNK (S_LEN / CHUNK)

typedef float f2 __attribute__((ext_vector_type(2)));

// Clamp-free tanh: tanh(z) = 1 - 2/(e^{2z}+1).
__device__ __forceinline__ float fast_tanh(float z) {
    float e = __builtin_amdgcn_exp2f(z * 2.8853900817779268f);
    return fmaf(-2.0f, __builtin_amdgcn_rcpf(e + 1.0f), 1.0f);
}

// Compiler-generated lane broadcast (hazard handling by LLVM).
__device__ __forceinline__ float rdlane(float v, int lane) {
    return __uint_as_float(__builtin_amdgcn_readlane(__float_as_uint(v), lane));
}

// FINAL (= R13, the measured optimum of this topology; R14/R15/R16
// perturbations all regressed: 5865/6046/5931 vs 5826 µs).
// One block = one chain: 256 threads = 4 waves, 1 wave/SIMD.
// K split ACROSS waves (wave w owns rows [32w,32w+32)); lane l owns units
// jA=l, jB=l+64; weights row-packed {W2[i][jA],W2[i][jB]} as 32 f2 =
// 64 arch VGPRs, resident via waves_per_eu(1,1) (VGPR_Count=132).
// h1 broadcast via readlane (VALU pipe) — no h-LDS round-trip; ONE
// barrier per step for the parity-double-buffered pv exchange; finish
// (tanh2, W3 dot, 6-stage DPP reduce, readlane) redundant in all 4 waves.
// Per-step serial floor ~853 cyc: MAC issue 128/SIMD + barrier/DS/
// transcendental latency. bf16/MFMA rejected on error-accumulation
// arithmetic (2e-3/step random-walks past the 2.8e-3 threshold).
__attribute__((amdgpu_waves_per_eu(1, 1)))
__global__ __launch_bounds__(NTHR, 1) void ode_scan_kernel(
    const float* __restrict__ x,
    const float* __restrict__ W1, const float* __restrict__ b1,
    const float* __restrict__ W2, const float* __restrict__ b2,
    const float* __restrict__ W3, const float* __restrict__ b3,
    float* __restrict__ out)
{
    const int tid  = threadIdx.x;
    const int bb   = blockIdx.x;     // batch chain index
    const int l    = tid & 63;       // lane
    const int w    = tid >> 6;       // wave = K-quarter
    const int koff = w << 5;         // first K-row of this wave
    const int jA   = l;              // owned units
    const int jB   = l + 64;
    const int row  = koff + (l & 31);// layer-1 row (lanes 32.. duplicate)

    __shared__ __align__(16) f2    lds_p[2][4][64]; // [par][wave][lane]={pA,pB}
    __shared__ float lds_x[2][CHUNK];

    // layer-1 constants for this lane's K-row
    const float c1  = W1[row];          // y coefficient (row 0 of W1)
    const float w1x = W1[HID + row];    // x coefficient (row 1 of W1)
    const float b1r = b1[row];
    // layer-2/3 constants for the two owned units
    const float b2A = b2[jA], b2B = b2[jB];
    const float w3A = W3[jA], w3B = W3[jB];
    const float b3s = b3[0];

    // 32 rows x {unitA, unitB}: w##r##_##t = {W2[koff+4r+t][jA], ..[jB]}.
#define REP8(M) M(0) M(1) M(2) M(3) M(4) M(5) M(6) M(7)
#define DECLW(r) \
    f2 w##r##_0 = { W2[(koff+4*(r)+0)*HID + jA], W2[(koff+4*(r)+0)*HID + jB] }; \
    f2 w##r##_1 = { W2[(koff+4*(r)+1)*HID + jA], W2[(koff+4*(r)+1)*HID + jB] }; \
    f2 w##r##_2 = { W2[(koff+4*(r)+2)*HID + jA], W2[(koff+4*(r)+2)*HID + jB] }; \
    f2 w##r##_3 = { W2[(koff+4*(r)+3)*HID + jA], W2[(koff+4*(r)+3)*HID + jB] };
    REP8(DECLW)

    // Preload x chunk 0: lds_x[0][t] = x[t][bb].
    lds_x[0][tid] = x[tid * BATCH + bb];
    __syncthreads();

    // Carried state: y (pre-update), svb (last step's Δy), base (= c1*y + ax
    // for the CURRENT step), ycap (captured output history).
    float y    = 0.0f;
    float ycap = 0.0f;
    float svb  = 0.0f;
    float base = fmaf(w1x, lds_x[0][0], b1r);  // = ax_0 (y_0 = 0)
    int   cur  = 0;

    for (int c = 0; c < NCHUNK; ++c) {
        // Refill other x buffer with next chunk (dup-load last, unused).
        int nb = (c + 1 < NCHUNK) ? (c + 1) : c;
        float xf = x[(nb * CHUNK + tid) * BATCH + bb];
        lds_x[cur ^ 1][tid] = xf;

#pragma unroll 1
        for (int s = 0; s < CHUNK; ++s) {
            // ---- layer 1: z = c1*y_n + ax_n = base + c1*svb_{n-1} ----
            float h1 = fast_tanh(fmaf(c1, svb, base));

            y += svb;                  // y_n (off critical path)

            // ---- layer 2 (quarter-K x 2 units): readlane broadcast +
            //      one pk-FMA per row covering both units ----
            f2 a0 = {0.f,0.f}, a1 = {0.f,0.f}, a2 = {0.f,0.f}, a3 = {0.f,0.f};
#define MACR(r) { \
            float h0_ = rdlane(h1, 4*(r)+0); f2 s0_ = { h0_, h0_ }; \
            a0 = __builtin_elementwise_fma(s0_, w##r##_0, a0); \
            float h1_ = rdlane(h1, 4*(r)+1); f2 s1_ = { h1_, h1_ }; \
            a1 = __builtin_elementwise_fma(s1_, w##r##_1, a1); \
            float h2_ = rdlane(h1, 4*(r)+2); f2 s2_ = { h2_, h2_ }; \
            a2 = __builtin_elementwise_fma(s2_, w##r##_2, a2); \
            float h3_ = rdlane(h1, 4*(r)+3); f2 s3_ = { h3_, h3_ }; \
            a3 = __builtin_elementwise_fma(s3_, w##r##_3, a3); }
            REP8(MACR)

            f2 pv = (a0 + a1) + (a2 + a3);   // {pA, pB} for this K-quarter

            // ---- publish partials ASAP ----
            const int buf = s & 1;           // parity double-buffer: WAR-safe
            lds_p[buf][w][l] = pv;           // ds_write_b64

            // ---- off-path work fills the pre-barrier drain window ----
            float xn  = (s < CHUNK - 1) ? lds_x[cur][s + 1] : lds_x[cur ^ 1][0];
            float axn = fmaf(w1x, xn, b1r);  // ax_{n+1}
            base = fmaf(c1, y, axn);         // c1*y_n + ax_{n+1}

            __syncthreads();                 // the ONE barrier per step

            // ---- finish: all 4 waves redundantly, bit-identical ----
            f2 r0 = lds_p[buf][0][l];
            f2 r1 = lds_p[buf][1][l];
            f2 r2 = lds_p[buf][2][l];
            f2 r3 = lds_p[buf][3][l];
            f2 q  = (r0 + r1) + (r2 + r3);   // {sum_jA, sum_jB} over K=128
            float h2A = fast_tanh(q.x + b2A);
            float h2B = fast_tanh(q.y + b2B);
            float p   = fmaf(h2A, w3A, h2B * w3B);

            // 64-lane DPP sum (covers all 128 units) -> lane 63
            asm volatile(
                "s_nop 1\n\t"
                "v_add_f32 %0, %0, %0 row_shr:1 bound_ctrl:0\n\t"
                "s_nop 1\n\t"
                "v_add_f32 %0, %0, %0 row_shr:2 bound_ctrl:0\n\t"
                "s_nop 1\n\t"
                "v_add_f32 %0, %0, %0 row_shr:4 bank_mask:0xe\n\t"
                "s_nop 1\n\t"
                "v_add_f32 %0, %0, %0 row_shr:8 bank_mask:0xc\n\t"
                "s_nop 1\n\t"
                "v_add_f32 %0, %0, %0 row_bcast:15 row_mask:0xa\n\t"
                "s_nop 1\n\t"
                "v_add_f32 %0, %0, %0 row_bcast:31 row_mask:0xc\n\t"
                : "+v"(p));
            float sv = rdlane(p, 63);        // compiler readlane (hazard-safe)

            svb = sv + b3s;                  // Δy_n; feeds next layer-1 directly
            ycap = (tid == s) ? (y + svb) : ycap;  // y_{n+1} capture (off-path)
        }
        out[(c * CHUNK + tid) * BATCH + bb] = ycap;   // 256 steps per store
        cur ^= 1;
    }
}

extern "C" void kernel_launch(void* const* d_in, const int* in_sizes, int n_in,
                              void* d_out, int out_size, void* d_ws, size_t ws_size,
                              hipStream_t stream) {
    const float* x  = (const float*)d_in[0];
    const float* W1 = (const float*)d_in[1];
    const float* b1 = (const float*)d_in[2];
    const float* W2 = (const float*)d_in[3];
    const float* b2 = (const float*)d_in[4];
    const float* W3 = (const float*)d_in[5];
    const float* b3 = (const float*)d_in[6];
    float* out = (float*)d_out;

    hipLaunchKernelGGL(ode_scan_kernel, dim3(BATCH), dim3(NTHR), 0, stream,
                       x, W1, b1, W2, b2, W3, b3, out);
}